// Round 1
// baseline (689.316 us; speedup 1.0000x reference)
//
#include <hip/hip_runtime.h>
#include <stdint.h>
#include <stddef.h>

#define NN 50000
#define NE 800000
#define NG 128
#define SCAN_B 512
#define NB_SCAN ((NN + SCAN_B - 1) / SCAN_B)   // 98

// ---------------- utility kernels ----------------
static __global__ void zero_int_kernel(int* __restrict__ p, int n) {
    int i = blockIdx.x * 256 + threadIdx.x;
    if (i < n) p[i] = 0;
}
static __global__ void zero_f_kernel(float* __restrict__ p, int n) {
    int i = blockIdx.x * 256 + threadIdx.x;
    if (i < n) p[i] = 0.f;
}

// degree histogram over dst
static __global__ void hist_kernel(const int* __restrict__ dst, int* __restrict__ deg) {
    int e = blockIdx.x * 256 + threadIdx.x;
    if (e < NE) atomicAdd(&deg[dst[e]], 1);
}

// ---------------- exclusive scan (3-kernel) ----------------
static __global__ void scan_block_kernel(const int* __restrict__ deg, int* __restrict__ offs,
                                         int* __restrict__ bsums) {
    __shared__ int s[SCAN_B];
    int tid = threadIdx.x;
    int i = blockIdx.x * SCAN_B + tid;
    int v = (i < NN) ? deg[i] : 0;
    s[tid] = v;
    __syncthreads();
    for (int off = 1; off < SCAN_B; off <<= 1) {
        int t = (tid >= off) ? s[tid - off] : 0;
        __syncthreads();
        s[tid] += t;
        __syncthreads();
    }
    if (i < NN) offs[i] = s[tid] - v;           // exclusive
    if (tid == SCAN_B - 1) bsums[blockIdx.x] = s[tid];
}

static __global__ void scan_sums_kernel(int* __restrict__ bsums) {
    __shared__ int s[128];
    int tid = threadIdx.x;
    int v = (tid < NB_SCAN) ? bsums[tid] : 0;
    s[tid] = v;
    __syncthreads();
    for (int off = 1; off < 128; off <<= 1) {
        int t = (tid >= off) ? s[tid - off] : 0;
        __syncthreads();
        s[tid] += t;
        __syncthreads();
    }
    if (tid < NB_SCAN) bsums[tid] = s[tid] - v; // exclusive
}

static __global__ void add_base_kernel(int* __restrict__ offs, const int* __restrict__ bsums,
                                       int* __restrict__ cursor) {
    int i = blockIdx.x * SCAN_B + threadIdx.x;
    if (i < NN) { offs[i] += bsums[blockIdx.x]; cursor[i] = 0; }
}

static __global__ void fill_csr_kernel(const int* __restrict__ src, const int* __restrict__ dst,
                                       const int* __restrict__ offs, int* __restrict__ cursor,
                                       int* __restrict__ csr) {
    int e = blockIdx.x * 256 + threadIdx.x;
    if (e < NE) {
        int d = dst[e];
        int p = atomicAdd(&cursor[d], 1);
        csr[offs[d] + p] = src[e];
    }
}

// ---------------- GEMM: out[i][o] = dot(h[i], W[o]) (+ bias) ----------------
// W is [DOUT, DIN] row-major. Weights staged transposed in LDS [c][o] so that
// consecutive-o lanes read consecutive LDS addresses (conflict-free).
template <int DIN, int DOUT, int SLOTS, int NL, bool ADD_BIAS>
__launch_bounds__(SLOTS* DOUT) static __global__
void gemm_kernel(const float* __restrict__ h, const float* __restrict__ W,
                 const float* __restrict__ bias, float* __restrict__ out) {
    __shared__ float w_s[DIN * DOUT];            // [c][o]
    __shared__ float h_s[SLOTS * NL * DIN];      // node rows
    constexpr int NT = SLOTS * DOUT;
    int tid = threadIdx.x;
    for (int idx = tid; idx < DIN * DOUT; idx += NT) {
        int c = idx / DOUT, o = idx % DOUT;
        w_s[idx] = W[o * DIN + c];               // LDS-write coalesced; global read L2-hot
    }
    int o = tid % DOUT, slot = tid / DOUT;
    float bv = ADD_BIAS ? bias[o] : 0.f;
    constexpr int TILE = SLOTS * NL;
    int ntiles = (NN + TILE - 1) / TILE;
    for (int t = blockIdx.x; t < ntiles; t += gridDim.x) {
        int base = t * TILE;
        __syncthreads();                         // protect h_s (and w_s first iter)
        for (int idx = tid; idx < TILE * DIN; idx += NT) {
            int node = base + idx / DIN;
            h_s[idx] = (node < NN) ? h[node * DIN + idx % DIN] : 0.f;
        }
        __syncthreads();
        float acc[NL];
#pragma unroll
        for (int q = 0; q < NL; q++) acc[q] = bv;
#pragma unroll 4
        for (int c = 0; c < DIN; c++) {
            float wv = w_s[c * DOUT + o];
#pragma unroll
            for (int q = 0; q < NL; q++)
                acc[q] = fmaf(h_s[(slot * NL + q) * DIN + c], wv, acc[q]);
        }
#pragma unroll
        for (int q = 0; q < NL; q++) {
            int node = base + slot * NL + q;
            if (node < NN) out[node * DOUT + o] = acc[q];
        }
    }
}

// ---------------- aggregation: out[i] = relu?( mean_{j in N(i)} tl[j] + tr[i] ) ----------------
// 32 lanes per node, PT = D/32 features per lane; neighbor rows are coalesced 128B segments.
template <int D, int PT, bool RELU>
static __global__ void agg_kernel(const float* __restrict__ tl, const float* __restrict__ tr,
                                  const int* __restrict__ offs, const int* __restrict__ deg,
                                  const int* __restrict__ csr, float* __restrict__ out) {
    int gtid = blockIdx.x * blockDim.x + threadIdx.x;
    int node = gtid >> 5;
    int lane = threadIdx.x & 31;
    if (node >= NN) return;
    int off = offs[node], dg = deg[node];
    float acc[PT];
#pragma unroll
    for (int q = 0; q < PT; q++) acc[q] = 0.f;
    for (int k = 0; k < dg; k++) {
        const float* row = tl + (size_t)csr[off + k] * D;
#pragma unroll
        for (int q = 0; q < PT; q++) acc[q] += row[lane + 32 * q];
    }
    float s = 1.f / (float)max(dg, 1);
    const float* trr = tr + (size_t)node * D;
    float* op = out + (size_t)node * D;
#pragma unroll
    for (int q = 0; q < PT; q++) {
        float v = fmaf(acc[q], s, trr[lane + 32 * q]);
        if (RELU) v = fmaxf(v, 0.f);
        op[lane + 32 * q] = v;
    }
}

// ---------------- pooling over sorted batch ids ----------------
static __global__ void pool_kernel(const float* __restrict__ h, const int* __restrict__ batch,
                                   float* __restrict__ accum, int* __restrict__ cnt) {
    int per = (NN + gridDim.x - 1) / gridDim.x;
    int start = blockIdx.x * per;
    int end = min(start + per, NN);
    if (start >= end) return;
    int c = threadIdx.x;                         // 64 features
    int gcur = batch[start];
    float acc = 0.f;
    int count = 0;
    for (int i = start; i < end; i++) {
        int g = batch[i];
        if (g != gcur) {
            atomicAdd(&accum[gcur * 64 + c], acc);
            if (c == 0) atomicAdd(&cnt[gcur], count);
            acc = 0.f; count = 0; gcur = g;
        }
        acc += h[(size_t)i * 64 + c];
        count++;
    }
    atomicAdd(&accum[gcur * 64 + c], acc);
    if (c == 0) atomicAdd(&cnt[gcur], count);
}

static __global__ void finalize_kernel(const float* __restrict__ accum, const int* __restrict__ cnt,
                                       float* __restrict__ out) {
    int i = blockIdx.x * 256 + threadIdx.x;
    if (i < NG * 64) {
        int g = i >> 6;
        out[i] = accum[i] / (float)max(cnt[g], 1);
    }
}

// ---------------- launch ----------------
extern "C" void kernel_launch(void* const* d_in, const int* in_sizes, int n_in,
                              void* d_out, int out_size, void* d_ws, size_t ws_size,
                              hipStream_t stream) {
    (void)in_sizes; (void)n_in; (void)out_size; (void)ws_size;
    const float* x   = (const float*)d_in[0];
    const int*   ei  = (const int*)d_in[1];
    const int*   bat = (const int*)d_in[2];
    const float* Wl0 = (const float*)d_in[3];
    const float* b0  = (const float*)d_in[4];
    const float* Wr0 = (const float*)d_in[5];
    const float* Wl1 = (const float*)d_in[6];
    const float* b1  = (const float*)d_in[7];
    const float* Wr1 = (const float*)d_in[8];
    const float* Wl2 = (const float*)d_in[9];
    const float* b2  = (const float*)d_in[10];
    const float* Wr2 = (const float*)d_in[11];
    float* out = (float*)d_out;
    const int* src = ei;
    const int* dst = ei + NE;

    char* p = (char*)d_ws;
    auto carve = [&](size_t bytes) -> char* {
        char* r = p;
        p += (bytes + 255) & ~(size_t)255;
        return r;
    };
    int*   deg    = (int*)carve((size_t)NN * 4);
    int*   offs   = (int*)carve((size_t)NN * 4);
    int*   cursor = (int*)carve((size_t)NN * 4);
    int*   bsums  = (int*)carve(128 * 4);
    int*   csr    = (int*)carve((size_t)NE * 4);
    int*   cnt    = (int*)carve(NG * 4);
    float* accum  = (float*)carve((size_t)NG * 64 * 4);
    float* tl     = (float*)carve((size_t)NN * 96 * 4);
    float* tr     = (float*)carve((size_t)NN * 96 * 4);
    float* H      = (float*)carve((size_t)NN * 96 * 4);

    dim3 b256(256);
    zero_int_kernel<<<dim3((NN + 255) / 256), b256, 0, stream>>>(deg, NN);
    zero_int_kernel<<<dim3(1), b256, 0, stream>>>(cnt, NG);
    zero_f_kernel<<<dim3((NG * 64 + 255) / 256), b256, 0, stream>>>(accum, NG * 64);

    hist_kernel<<<dim3((NE + 255) / 256), b256, 0, stream>>>(dst, deg);
    scan_block_kernel<<<dim3(NB_SCAN), dim3(SCAN_B), 0, stream>>>(deg, offs, bsums);
    scan_sums_kernel<<<dim3(1), dim3(128), 0, stream>>>(bsums);
    add_base_kernel<<<dim3(NB_SCAN), dim3(SCAN_B), 0, stream>>>(offs, bsums, cursor);
    fill_csr_kernel<<<dim3((NE + 255) / 256), b256, 0, stream>>>(src, dst, offs, cursor, csr);

    dim3 aggGrid((NN * 32 + 255) / 256);

    // layer 0: 96 -> 96, relu
    gemm_kernel<96, 96, 2, 4, false><<<512, 192, 0, stream>>>(x, Wl0, nullptr, tl);
    gemm_kernel<96, 96, 2, 4, true ><<<512, 192, 0, stream>>>(x, Wr0, b0, tr);
    agg_kernel<96, 3, true><<<aggGrid, b256, 0, stream>>>(tl, tr, offs, deg, csr, H);
    // layer 1: 96 -> 96, relu
    gemm_kernel<96, 96, 2, 4, false><<<512, 192, 0, stream>>>(H, Wl1, nullptr, tl);
    gemm_kernel<96, 96, 2, 4, true ><<<512, 192, 0, stream>>>(H, Wr1, b1, tr);
    agg_kernel<96, 3, true><<<aggGrid, b256, 0, stream>>>(tl, tr, offs, deg, csr, H);
    // layer 2: 96 -> 64, no relu
    gemm_kernel<96, 64, 3, 4, false><<<512, 192, 0, stream>>>(H, Wl2, nullptr, tl);
    gemm_kernel<96, 64, 3, 4, true ><<<512, 192, 0, stream>>>(H, Wr2, b2, tr);
    agg_kernel<64, 2, false><<<aggGrid, b256, 0, stream>>>(tl, tr, offs, deg, csr, H);

    pool_kernel<<<dim3(512), dim3(64), 0, stream>>>(H, bat, accum, cnt);
    finalize_kernel<<<dim3((NG * 64 + 255) / 256), b256, 0, stream>>>(accum, cnt, out);
}

// Round 2
// 662.105 us; speedup vs baseline: 1.0411x; 1.0411x over previous
//
#include <hip/hip_runtime.h>
#include <stdint.h>
#include <stddef.h>

#define NN 50000
#define NE 800000
#define NG 128
#define SCAN_B 512
#define NB_SCAN ((NN + SCAN_B - 1) / SCAN_B)   // 98

// ---------------- utility kernels ----------------
// zero deg[NN], cnt[NG], accum[NG*64] in one launch
static __global__ void zero_all_kernel(int* __restrict__ deg, int* __restrict__ cnt,
                                       float* __restrict__ accum) {
    int i = blockIdx.x * 256 + threadIdx.x;
    if (i < NN) deg[i] = 0;
    if (i < NG) cnt[i] = 0;
    if (i < NG * 64) accum[i] = 0.f;
}

// degree histogram over dst
static __global__ void hist_kernel(const int* __restrict__ dst, int* __restrict__ deg) {
    int e = blockIdx.x * 256 + threadIdx.x;
    if (e < NE) atomicAdd(&deg[dst[e]], 1);
}

// ---------------- exclusive scan (3-kernel) ----------------
static __global__ void scan_block_kernel(const int* __restrict__ deg, int* __restrict__ offs,
                                         int* __restrict__ bsums) {
    __shared__ int s[SCAN_B];
    int tid = threadIdx.x;
    int i = blockIdx.x * SCAN_B + tid;
    int v = (i < NN) ? deg[i] : 0;
    s[tid] = v;
    __syncthreads();
    for (int off = 1; off < SCAN_B; off <<= 1) {
        int t = (tid >= off) ? s[tid - off] : 0;
        __syncthreads();
        s[tid] += t;
        __syncthreads();
    }
    if (i < NN) offs[i] = s[tid] - v;           // exclusive
    if (tid == SCAN_B - 1) bsums[blockIdx.x] = s[tid];
}

static __global__ void scan_sums_kernel(int* __restrict__ bsums) {
    __shared__ int s[128];
    int tid = threadIdx.x;
    int v = (tid < NB_SCAN) ? bsums[tid] : 0;
    s[tid] = v;
    __syncthreads();
    for (int off = 1; off < 128; off <<= 1) {
        int t = (tid >= off) ? s[tid - off] : 0;
        __syncthreads();
        s[tid] += t;
        __syncthreads();
    }
    if (tid < NB_SCAN) bsums[tid] = s[tid] - v; // exclusive
}

static __global__ void add_base_kernel(int* __restrict__ offs, const int* __restrict__ bsums,
                                       int* __restrict__ cursor) {
    int i = blockIdx.x * SCAN_B + threadIdx.x;
    if (i < NN) { offs[i] += bsums[blockIdx.x]; cursor[i] = 0; }
}

static __global__ void fill_csr_kernel(const int* __restrict__ src, const int* __restrict__ dst,
                                       const int* __restrict__ offs, int* __restrict__ cursor,
                                       int* __restrict__ csr) {
    int e = blockIdx.x * 256 + threadIdx.x;
    if (e < NE) {
        int d = dst[e];
        int p = atomicAdd(&cursor[d], 1);
        csr[offs[d] + p] = src[e];
    }
}

// ---------------- fused transform: tl = h@Wl.T ; tr = h@Wr.T + b ----------------
// Thread = one node row (kept in VGPRs). Weight accesses are wave-uniform ->
// compiler emits s_load; inner loop is pure v_fmac_f32 with scalar weight
// operand (16 independent chains per chunk -> one wave saturates the SIMD).
// gridDim.y = GROUPS splits the 2*DOUT outputs for SIMD occupancy (3128 waves).
template <int DIN, int DOUT, int GROUPS>
__launch_bounds__(64) static __global__
void transform_kernel(const float* __restrict__ h, const float* __restrict__ Wl,
                      const float* __restrict__ bias, const float* __restrict__ Wr,
                      float* __restrict__ tl, float* __restrict__ tr) {
    constexpr int TOT = 2 * DOUT;
    constexpr int PER = TOT / GROUPS;          // outputs this group computes
    constexpr int NCH = PER / 16;              // chunks of 16
    int node = blockIdx.x * 64 + threadIdx.x;
    if (node >= NN) return;
    int g = blockIdx.y;

    float hr[DIN];
    const float4* hp = (const float4*)(h + (size_t)node * DIN);
#pragma unroll
    for (int q = 0; q < DIN / 4; q++) {
        float4 v = hp[q];
        hr[4 * q + 0] = v.x; hr[4 * q + 1] = v.y;
        hr[4 * q + 2] = v.z; hr[4 * q + 3] = v.w;
    }

#pragma unroll 1
    for (int ch = 0; ch < NCH; ch++) {
        int obase = g * PER + ch * 16;         // global output index [0, 2*DOUT)
        bool is_r = obase >= DOUT;
        const float* __restrict__ W = is_r ? Wr : Wl;
        float* __restrict__ outp = is_r ? tr : tl;
        int ob = is_r ? (obase - DOUT) : obase;
        float acc[16];
#pragma unroll
        for (int o = 0; o < 16; o++) acc[o] = is_r ? bias[ob + o] : 0.f;
#pragma unroll
        for (int c = 0; c < DIN; c++) {
#pragma unroll
            for (int o = 0; o < 16; o++)
                acc[o] = fmaf(hr[c], W[(ob + o) * DIN + c], acc[o]);
        }
        float4* op = (float4*)(outp + (size_t)node * DOUT + ob);
#pragma unroll
        for (int q = 0; q < 4; q++)
            op[q] = make_float4(acc[4 * q], acc[4 * q + 1], acc[4 * q + 2], acc[4 * q + 3]);
    }
}

// ---------------- aggregation: out[i] = relu?( mean_{j in N(i)} tl[j] + tr[i] ) ----------------
// 32 lanes per node, PT = D/32 features per lane; neighbor rows are coalesced
// 128B segments. 4x unrolled so ~12 row loads are in flight per iteration.
template <int D, int PT, bool RELU>
static __global__ void agg_kernel(const float* __restrict__ tl, const float* __restrict__ tr,
                                  const int* __restrict__ offs, const int* __restrict__ deg,
                                  const int* __restrict__ csr, float* __restrict__ out) {
    int gtid = blockIdx.x * blockDim.x + threadIdx.x;
    int node = gtid >> 5;
    int lane = threadIdx.x & 31;
    if (node >= NN) return;
    int off = offs[node], dg = deg[node];
    float acc[PT];
#pragma unroll
    for (int q = 0; q < PT; q++) acc[q] = 0.f;
    int k = 0;
    for (; k + 4 <= dg; k += 4) {
        int i0 = csr[off + k + 0];
        int i1 = csr[off + k + 1];
        int i2 = csr[off + k + 2];
        int i3 = csr[off + k + 3];
        const float* r0 = tl + (size_t)i0 * D;
        const float* r1 = tl + (size_t)i1 * D;
        const float* r2 = tl + (size_t)i2 * D;
        const float* r3 = tl + (size_t)i3 * D;
#pragma unroll
        for (int q = 0; q < PT; q++) {
            acc[q] += r0[lane + 32 * q];
            acc[q] += r1[lane + 32 * q];
            acc[q] += r2[lane + 32 * q];
            acc[q] += r3[lane + 32 * q];
        }
    }
    for (; k < dg; k++) {
        const float* row = tl + (size_t)csr[off + k] * D;
#pragma unroll
        for (int q = 0; q < PT; q++) acc[q] += row[lane + 32 * q];
    }
    float s = 1.f / (float)max(dg, 1);
    const float* trr = tr + (size_t)node * D;
    float* op = out + (size_t)node * D;
#pragma unroll
    for (int q = 0; q < PT; q++) {
        float v = fmaf(acc[q], s, trr[lane + 32 * q]);
        if (RELU) v = fmaxf(v, 0.f);
        op[lane + 32 * q] = v;
    }
}

// ---------------- pooling over sorted batch ids ----------------
static __global__ void pool_kernel(const float* __restrict__ h, const int* __restrict__ batch,
                                   float* __restrict__ accum, int* __restrict__ cnt) {
    int per = (NN + gridDim.x - 1) / gridDim.x;
    int start = blockIdx.x * per;
    int end = min(start + per, NN);
    if (start >= end) return;
    int c = threadIdx.x;                         // 64 features
    int gcur = batch[start];
    float acc = 0.f;
    int count = 0;
    for (int i = start; i < end; i++) {
        int g = batch[i];
        if (g != gcur) {
            atomicAdd(&accum[gcur * 64 + c], acc);
            if (c == 0) atomicAdd(&cnt[gcur], count);
            acc = 0.f; count = 0; gcur = g;
        }
        acc += h[(size_t)i * 64 + c];
        count++;
    }
    atomicAdd(&accum[gcur * 64 + c], acc);
    if (c == 0) atomicAdd(&cnt[gcur], count);
}

static __global__ void finalize_kernel(const float* __restrict__ accum, const int* __restrict__ cnt,
                                       float* __restrict__ out) {
    int i = blockIdx.x * 256 + threadIdx.x;
    if (i < NG * 64) {
        int g = i >> 6;
        out[i] = accum[i] / (float)max(cnt[g], 1);
    }
}

// ---------------- launch ----------------
extern "C" void kernel_launch(void* const* d_in, const int* in_sizes, int n_in,
                              void* d_out, int out_size, void* d_ws, size_t ws_size,
                              hipStream_t stream) {
    (void)in_sizes; (void)n_in; (void)out_size; (void)ws_size;
    const float* x   = (const float*)d_in[0];
    const int*   ei  = (const int*)d_in[1];
    const int*   bat = (const int*)d_in[2];
    const float* Wl0 = (const float*)d_in[3];
    const float* b0  = (const float*)d_in[4];
    const float* Wr0 = (const float*)d_in[5];
    const float* Wl1 = (const float*)d_in[6];
    const float* b1  = (const float*)d_in[7];
    const float* Wr1 = (const float*)d_in[8];
    const float* Wl2 = (const float*)d_in[9];
    const float* b2  = (const float*)d_in[10];
    const float* Wr2 = (const float*)d_in[11];
    float* out = (float*)d_out;
    const int* src = ei;
    const int* dst = ei + NE;

    char* p = (char*)d_ws;
    auto carve = [&](size_t bytes) -> char* {
        char* r = p;
        p += (bytes + 255) & ~(size_t)255;
        return r;
    };
    int*   deg    = (int*)carve((size_t)NN * 4);
    int*   offs   = (int*)carve((size_t)NN * 4);
    int*   cursor = (int*)carve((size_t)NN * 4);
    int*   bsums  = (int*)carve(128 * 4);
    int*   csr    = (int*)carve((size_t)NE * 4);
    int*   cnt    = (int*)carve(NG * 4);
    float* accum  = (float*)carve((size_t)NG * 64 * 4);
    float* tl     = (float*)carve((size_t)NN * 96 * 4);
    float* tr     = (float*)carve((size_t)NN * 96 * 4);
    float* H      = (float*)carve((size_t)NN * 96 * 4);

    dim3 b256(256);
    zero_all_kernel<<<dim3((NN + 255) / 256), b256, 0, stream>>>(deg, cnt, accum);

    hist_kernel<<<dim3((NE + 255) / 256), b256, 0, stream>>>(dst, deg);
    scan_block_kernel<<<dim3(NB_SCAN), dim3(SCAN_B), 0, stream>>>(deg, offs, bsums);
    scan_sums_kernel<<<dim3(1), dim3(128), 0, stream>>>(bsums);
    add_base_kernel<<<dim3(NB_SCAN), dim3(SCAN_B), 0, stream>>>(offs, bsums, cursor);
    fill_csr_kernel<<<dim3((NE + 255) / 256), b256, 0, stream>>>(src, dst, offs, cursor, csr);

    dim3 aggGrid((NN * 32 + 255) / 256);
    dim3 tGrid((NN + 63) / 64, 4);               // 782 x 4 -> 3128 waves (~3/SIMD)
    dim3 tBlock(64);

    // layer 0: 96 -> 96, relu
    transform_kernel<96, 96, 4><<<tGrid, tBlock, 0, stream>>>(x, Wl0, b0, Wr0, tl, tr);
    agg_kernel<96, 3, true><<<aggGrid, b256, 0, stream>>>(tl, tr, offs, deg, csr, H);
    // layer 1: 96 -> 96, relu
    transform_kernel<96, 96, 4><<<tGrid, tBlock, 0, stream>>>(H, Wl1, b1, Wr1, tl, tr);
    agg_kernel<96, 3, true><<<aggGrid, b256, 0, stream>>>(tl, tr, offs, deg, csr, H);
    // layer 2: 96 -> 64, no relu
    transform_kernel<96, 64, 4><<<tGrid, tBlock, 0, stream>>>(H, Wl2, b2, Wr2, tl, tr);
    agg_kernel<64, 2, false><<<aggGrid, b256, 0, stream>>>(tl, tr, offs, deg, csr, H);

    pool_kernel<<<dim3(512), dim3(64), 0, stream>>>(H, bat, accum, cnt);
    finalize_kernel<<<dim3((NG * 64 + 255) / 256), b256, 0, stream>>>(accum, cnt, out);
}

// Round 3
// 442.988 us; speedup vs baseline: 1.5561x; 1.4946x over previous
//
#include <hip/hip_runtime.h>
#include <stdint.h>
#include <stddef.h>

#define NN 50000
#define NE 800000
#define NG 128
#define SCAN_B 512
#define NB_SCAN ((NN + SCAN_B - 1) / SCAN_B)   // 98

// ---------------- utility kernels ----------------
// zero deg[NN], cnt[NG], accum[NG*64] in one launch
static __global__ void zero_all_kernel(int* __restrict__ deg, int* __restrict__ cnt,
                                       float* __restrict__ accum) {
    int i = blockIdx.x * 256 + threadIdx.x;
    if (i < NN) deg[i] = 0;
    if (i < NG) cnt[i] = 0;
    if (i < NG * 64) accum[i] = 0.f;
}

// degree histogram over dst
static __global__ void hist_kernel(const int* __restrict__ dst, int* __restrict__ deg) {
    int e = blockIdx.x * 256 + threadIdx.x;
    if (e < NE) atomicAdd(&deg[dst[e]], 1);
}

// ---------------- exclusive scan (3-kernel) ----------------
static __global__ void scan_block_kernel(const int* __restrict__ deg, int* __restrict__ offs,
                                         int* __restrict__ bsums) {
    __shared__ int s[SCAN_B];
    int tid = threadIdx.x;
    int i = blockIdx.x * SCAN_B + tid;
    int v = (i < NN) ? deg[i] : 0;
    s[tid] = v;
    __syncthreads();
    for (int off = 1; off < SCAN_B; off <<= 1) {
        int t = (tid >= off) ? s[tid - off] : 0;
        __syncthreads();
        s[tid] += t;
        __syncthreads();
    }
    if (i < NN) offs[i] = s[tid] - v;           // exclusive
    if (tid == SCAN_B - 1) bsums[blockIdx.x] = s[tid];
}

static __global__ void scan_sums_kernel(int* __restrict__ bsums) {
    __shared__ int s[128];
    int tid = threadIdx.x;
    int v = (tid < NB_SCAN) ? bsums[tid] : 0;
    s[tid] = v;
    __syncthreads();
    for (int off = 1; off < 128; off <<= 1) {
        int t = (tid >= off) ? s[tid - off] : 0;
        __syncthreads();
        s[tid] += t;
        __syncthreads();
    }
    if (tid < NB_SCAN) bsums[tid] = s[tid] - v; // exclusive
}

static __global__ void add_base_kernel(int* __restrict__ offs, const int* __restrict__ bsums,
                                       int* __restrict__ cursor) {
    int i = blockIdx.x * SCAN_B + threadIdx.x;
    if (i < NN) { offs[i] += bsums[blockIdx.x]; cursor[i] = 0; }
}

static __global__ void fill_csr_kernel(const int* __restrict__ src, const int* __restrict__ dst,
                                       const int* __restrict__ offs, int* __restrict__ cursor,
                                       int* __restrict__ csr) {
    int e = blockIdx.x * 256 + threadIdx.x;
    if (e < NE) {
        int d = dst[e];
        int p = atomicAdd(&cursor[d], 1);
        csr[offs[d] + p] = src[e];
    }
}

// ---------------- fused transform: tl = h@Wl.T ; tr = h@Wr.T + b ----------------
// Register-blocked LDS GEMM. Block = 256 threads covers 64 nodes x 2*DOUT outs.
// Thread tile = 4 nodes x NO outputs (NO = 2*DOUT/16). Output ownership is
// strided (o = tx + 16*j) so weight ds_read_b128 start banks land on
// 4*tx mod 32 -> 2 addresses per bank-group = conflict-free (m136). Row
// stride 36 floats (144 B) keeps 16B alignment and breaks the 32-bank wrap.
// Per 4-channel step: 16 x ds_read_b128 (~192 LDS cyc) feeds 192 FMAs
// (384 VALU cyc) -> VALU-bound.
template <int DIN, int DOUT, int NO>
__launch_bounds__(256, 3) static __global__
void transform_kernel(const float* __restrict__ h, const float* __restrict__ Wl,
                      const float* __restrict__ bias, const float* __restrict__ Wr,
                      float* __restrict__ tl, float* __restrict__ tr) {
    constexpr int OT = 2 * DOUT;               // 192 or 128
    constexpr int KB = 32;                     // K slice
    constexpr int S = 36;                      // padded LDS row stride (floats)
    __shared__ float h_s[64 * S];
    __shared__ float w_s[OT * S];
    int tid = threadIdx.x;
    int tx = tid & 15;                         // output group
    int ty = tid >> 4;                         // node group (0..15)
    int base = blockIdx.x * 64;

    float acc[4][NO];
#pragma unroll
    for (int i = 0; i < 4; i++)
#pragma unroll
        for (int j = 0; j < NO; j++) acc[i][j] = 0.f;

#pragma unroll 1
    for (int kb = 0; kb < DIN; kb += KB) {
        __syncthreads();
        // stage h slice: node = tid/4, channels (tid%4)*8 .. +7
        {
            int n = tid >> 2, c0 = (tid & 3) * 8;
            int node = base + n;
            float4 v0 = make_float4(0.f, 0.f, 0.f, 0.f), v1 = v0;
            if (node < NN) {
                const float4* src = (const float4*)(h + (size_t)node * DIN + kb + c0);
                v0 = src[0]; v1 = src[1];
            }
            float4* d = (float4*)&h_s[n * S + c0];
            d[0] = v0; d[1] = v1;
        }
        // stage w slice: rows [0,OT): first DOUT from Wl, rest from Wr
#pragma unroll
        for (int r = 0; r < OT / 64; r++) {
            int o = r * 64 + (tid >> 2), c0 = (tid & 3) * 8;
            const float* wrow = (o < DOUT) ? (Wl + (size_t)o * DIN)
                                           : (Wr + (size_t)(o - DOUT) * DIN);
            const float4* src = (const float4*)(wrow + kb + c0);
            float4* d = (float4*)&w_s[o * S + c0];
            d[0] = src[0]; d[1] = src[1];
        }
        __syncthreads();
#pragma unroll
        for (int cb = 0; cb < KB; cb += 4) {
            float4 hv[4];
#pragma unroll
            for (int i = 0; i < 4; i++)
                hv[i] = *(const float4*)&h_s[(ty * 4 + i) * S + cb];
            float4 wv[NO];
#pragma unroll
            for (int j = 0; j < NO; j++)
                wv[j] = *(const float4*)&w_s[(tx + 16 * j) * S + cb];
#pragma unroll
            for (int i = 0; i < 4; i++)
#pragma unroll
                for (int j = 0; j < NO; j++) {
                    acc[i][j] = fmaf(hv[i].x, wv[j].x, acc[i][j]);
                    acc[i][j] = fmaf(hv[i].y, wv[j].y, acc[i][j]);
                    acc[i][j] = fmaf(hv[i].z, wv[j].z, acc[i][j]);
                    acc[i][j] = fmaf(hv[i].w, wv[j].w, acc[i][j]);
                }
        }
    }
    // epilogue: o = tx + 16*j ; o < DOUT -> tl, else tr (+bias)
#pragma unroll
    for (int i = 0; i < 4; i++) {
        int node = base + ty * 4 + i;
        if (node >= NN) continue;
#pragma unroll
        for (int j = 0; j < NO; j++) {
            int o = tx + 16 * j;
            if (o < DOUT) tl[(size_t)node * DOUT + o] = acc[i][j];
            else tr[(size_t)node * DOUT + (o - DOUT)] = acc[i][j] + bias[o - DOUT];
        }
    }
}

// ---------------- aggregation: out[i] = relu?( mean_{j in N(i)} tl[j] + tr[i] ) ----------------
// 32 lanes per node, PT = D/32 features per lane; neighbor rows are coalesced
// 128B segments. 4x unrolled so ~12 row loads are in flight per iteration.
template <int D, int PT, bool RELU>
static __global__ void agg_kernel(const float* __restrict__ tl, const float* __restrict__ tr,
                                  const int* __restrict__ offs, const int* __restrict__ deg,
                                  const int* __restrict__ csr, float* __restrict__ out) {
    int gtid = blockIdx.x * blockDim.x + threadIdx.x;
    int node = gtid >> 5;
    int lane = threadIdx.x & 31;
    if (node >= NN) return;
    int off = offs[node], dg = deg[node];
    float acc[PT];
#pragma unroll
    for (int q = 0; q < PT; q++) acc[q] = 0.f;
    int k = 0;
    for (; k + 4 <= dg; k += 4) {
        int i0 = csr[off + k + 0];
        int i1 = csr[off + k + 1];
        int i2 = csr[off + k + 2];
        int i3 = csr[off + k + 3];
        const float* r0 = tl + (size_t)i0 * D;
        const float* r1 = tl + (size_t)i1 * D;
        const float* r2 = tl + (size_t)i2 * D;
        const float* r3 = tl + (size_t)i3 * D;
#pragma unroll
        for (int q = 0; q < PT; q++) {
            acc[q] += r0[lane + 32 * q];
            acc[q] += r1[lane + 32 * q];
            acc[q] += r2[lane + 32 * q];
            acc[q] += r3[lane + 32 * q];
        }
    }
    for (; k < dg; k++) {
        const float* row = tl + (size_t)csr[off + k] * D;
#pragma unroll
        for (int q = 0; q < PT; q++) acc[q] += row[lane + 32 * q];
    }
    float s = 1.f / (float)max(dg, 1);
    const float* trr = tr + (size_t)node * D;
    float* op = out + (size_t)node * D;
#pragma unroll
    for (int q = 0; q < PT; q++) {
        float v = fmaf(acc[q], s, trr[lane + 32 * q]);
        if (RELU) v = fmaxf(v, 0.f);
        op[lane + 32 * q] = v;
    }
}

// ---------------- pooling over sorted batch ids ----------------
static __global__ void pool_kernel(const float* __restrict__ h, const int* __restrict__ batch,
                                   float* __restrict__ accum, int* __restrict__ cnt) {
    int per = (NN + gridDim.x - 1) / gridDim.x;
    int start = blockIdx.x * per;
    int end = min(start + per, NN);
    if (start >= end) return;
    int c = threadIdx.x;                         // 64 features
    int gcur = batch[start];
    float acc = 0.f;
    int count = 0;
    for (int i = start; i < end; i++) {
        int g = batch[i];
        if (g != gcur) {
            atomicAdd(&accum[gcur * 64 + c], acc);
            if (c == 0) atomicAdd(&cnt[gcur], count);
            acc = 0.f; count = 0; gcur = g;
        }
        acc += h[(size_t)i * 64 + c];
        count++;
    }
    atomicAdd(&accum[gcur * 64 + c], acc);
    if (c == 0) atomicAdd(&cnt[gcur], count);
}

static __global__ void finalize_kernel(const float* __restrict__ accum, const int* __restrict__ cnt,
                                       float* __restrict__ out) {
    int i = blockIdx.x * 256 + threadIdx.x;
    if (i < NG * 64) {
        int g = i >> 6;
        out[i] = accum[i] / (float)max(cnt[g], 1);
    }
}

// ---------------- launch ----------------
extern "C" void kernel_launch(void* const* d_in, const int* in_sizes, int n_in,
                              void* d_out, int out_size, void* d_ws, size_t ws_size,
                              hipStream_t stream) {
    (void)in_sizes; (void)n_in; (void)out_size; (void)ws_size;
    const float* x   = (const float*)d_in[0];
    const int*   ei  = (const int*)d_in[1];
    const int*   bat = (const int*)d_in[2];
    const float* Wl0 = (const float*)d_in[3];
    const float* b0  = (const float*)d_in[4];
    const float* Wr0 = (const float*)d_in[5];
    const float* Wl1 = (const float*)d_in[6];
    const float* b1  = (const float*)d_in[7];
    const float* Wr1 = (const float*)d_in[8];
    const float* Wl2 = (const float*)d_in[9];
    const float* b2  = (const float*)d_in[10];
    const float* Wr2 = (const float*)d_in[11];
    float* out = (float*)d_out;
    const int* src = ei;
    const int* dst = ei + NE;

    char* p = (char*)d_ws;
    auto carve = [&](size_t bytes) -> char* {
        char* r = p;
        p += (bytes + 255) & ~(size_t)255;
        return r;
    };
    int*   deg    = (int*)carve((size_t)NN * 4);
    int*   offs   = (int*)carve((size_t)NN * 4);
    int*   cursor = (int*)carve((size_t)NN * 4);
    int*   bsums  = (int*)carve(128 * 4);
    int*   csr    = (int*)carve((size_t)NE * 4);
    int*   cnt    = (int*)carve(NG * 4);
    float* accum  = (float*)carve((size_t)NG * 64 * 4);
    float* tl     = (float*)carve((size_t)NN * 96 * 4);
    float* tr     = (float*)carve((size_t)NN * 96 * 4);
    float* H      = (float*)carve((size_t)NN * 96 * 4);

    dim3 b256(256);
    zero_all_kernel<<<dim3((NN + 255) / 256), b256, 0, stream>>>(deg, cnt, accum);

    hist_kernel<<<dim3((NE + 255) / 256), b256, 0, stream>>>(dst, deg);
    scan_block_kernel<<<dim3(NB_SCAN), dim3(SCAN_B), 0, stream>>>(deg, offs, bsums);
    scan_sums_kernel<<<dim3(1), dim3(128), 0, stream>>>(bsums);
    add_base_kernel<<<dim3(NB_SCAN), dim3(SCAN_B), 0, stream>>>(offs, bsums, cursor);
    fill_csr_kernel<<<dim3((NE + 255) / 256), b256, 0, stream>>>(src, dst, offs, cursor, csr);

    dim3 aggGrid((NN * 32 + 255) / 256);
    dim3 tGrid((NN + 63) / 64);                  // 782 blocks ~ 3/CU

    // layer 0: 96 -> 96, relu
    transform_kernel<96, 96, 12><<<tGrid, b256, 0, stream>>>(x, Wl0, b0, Wr0, tl, tr);
    agg_kernel<96, 3, true><<<aggGrid, b256, 0, stream>>>(tl, tr, offs, deg, csr, H);
    // layer 1: 96 -> 96, relu
    transform_kernel<96, 96, 12><<<tGrid, b256, 0, stream>>>(H, Wl1, b1, Wr1, tl, tr);
    agg_kernel<96, 3, true><<<aggGrid, b256, 0, stream>>>(tl, tr, offs, deg, csr, H);
    // layer 2: 96 -> 64, no relu
    transform_kernel<96, 64, 8><<<tGrid, b256, 0, stream>>>(H, Wl2, b2, Wr2, tl, tr);
    agg_kernel<64, 2, false><<<aggGrid, b256, 0, stream>>>(tl, tr, offs, deg, csr, H);

    pool_kernel<<<dim3(512), dim3(64), 0, stream>>>(H, bat, accum, cnt);
    finalize_kernel<<<dim3((NG * 64 + 255) / 256), b256, 0, stream>>>(accum, cnt, out);
}

// Round 4
// 330.464 us; speedup vs baseline: 2.0859x; 1.3405x over previous
//
#include <hip/hip_runtime.h>
#include <stdint.h>
#include <stddef.h>

#define NN 50000
#define NP 50048            // padded rows (782 * 64) so MFMA A-frag OOB reads stay in-buffer
#define NE 800000
#define NG 128
#define SCAN_B 512
#define NB_SCAN ((NN + SCAN_B - 1) / SCAN_B)   // 98

typedef __attribute__((ext_vector_type(8))) short bf16x8;
typedef __attribute__((ext_vector_type(4))) float f32x4;
typedef unsigned short ushort_t;
typedef unsigned int uint_t;

// float -> bf16 (RNE) and bf16x2 unpack helpers
static __device__ inline ushort_t f2b(float f) {
    union { float f; uint_t u; } v; v.f = f;
    uint_t r = v.u + 0x7FFFu + ((v.u >> 16) & 1u);
    return (ushort_t)(r >> 16);
}
static __device__ inline float blo(uint_t u) {
    union { uint_t u; float f; } v; v.u = u << 16; return v.f;
}
static __device__ inline float bhi(uint_t u) {
    union { uint_t u; float f; } v; v.u = u & 0xFFFF0000u; return v.f;
}

// ---------------- utility ----------------
static __global__ void zero_all_kernel(int* __restrict__ deg, int* __restrict__ cnt,
                                       float* __restrict__ accum) {
    int i = blockIdx.x * 256 + threadIdx.x;
    if (i < NN) deg[i] = 0;
    if (i < NG) cnt[i] = 0;
    if (i < NG * 64) accum[i] = 0.f;
}

// x fp32 -> bf16 (4 elems/thread)
static __global__ void cvt_bf16_kernel(const float* __restrict__ x, ushort_t* __restrict__ xb) {
    int i = (blockIdx.x * 256 + threadIdx.x) * 4;
    if (i + 3 < NN * 96) {
        float4 v = *(const float4*)(x + i);
        ushort_t o0 = f2b(v.x), o1 = f2b(v.y), o2 = f2b(v.z), o3 = f2b(v.w);
        uint_t lo = (uint_t)o0 | ((uint_t)o1 << 16);
        uint_t hi = (uint_t)o2 | ((uint_t)o3 << 16);
        *(uint2*)(xb + i) = make_uint2(lo, hi);
    }
}

static __global__ void hist_kernel(const int* __restrict__ dst, int* __restrict__ deg) {
    int e = blockIdx.x * 256 + threadIdx.x;
    if (e < NE) atomicAdd(&deg[dst[e]], 1);
}

// ---------------- exclusive scan (3-kernel) ----------------
static __global__ void scan_block_kernel(const int* __restrict__ deg, int* __restrict__ offs,
                                         int* __restrict__ bsums) {
    __shared__ int s[SCAN_B];
    int tid = threadIdx.x;
    int i = blockIdx.x * SCAN_B + tid;
    int v = (i < NN) ? deg[i] : 0;
    s[tid] = v;
    __syncthreads();
    for (int off = 1; off < SCAN_B; off <<= 1) {
        int t = (tid >= off) ? s[tid - off] : 0;
        __syncthreads();
        s[tid] += t;
        __syncthreads();
    }
    if (i < NN) offs[i] = s[tid] - v;
    if (tid == SCAN_B - 1) bsums[blockIdx.x] = s[tid];
}

static __global__ void scan_sums_kernel(int* __restrict__ bsums) {
    __shared__ int s[128];
    int tid = threadIdx.x;
    int v = (tid < NB_SCAN) ? bsums[tid] : 0;
    s[tid] = v;
    __syncthreads();
    for (int off = 1; off < 128; off <<= 1) {
        int t = (tid >= off) ? s[tid - off] : 0;
        __syncthreads();
        s[tid] += t;
        __syncthreads();
    }
    if (tid < NB_SCAN) bsums[tid] = s[tid] - v;
}

static __global__ void add_base_kernel(int* __restrict__ offs, const int* __restrict__ bsums,
                                       int* __restrict__ cursor) {
    int i = blockIdx.x * SCAN_B + threadIdx.x;
    if (i < NN) { offs[i] += bsums[blockIdx.x]; cursor[i] = 0; }
}

static __global__ void fill_csr_kernel(const int* __restrict__ src, const int* __restrict__ dst,
                                       const int* __restrict__ offs, int* __restrict__ cursor,
                                       int* __restrict__ csr) {
    int e = blockIdx.x * 256 + threadIdx.x;
    if (e < NE) {
        int d = dst[e];
        int p = atomicAdd(&cursor[d], 1);
        csr[offs[d] + p] = src[e];
    }
}

// ---------------- MFMA transform: tl = h@Wl.T ; tr = h@Wr.T + b (bf16 in/out, fp32 acc) ----
// Block = 256 thr = 4 waves, 64 nodes (16/wave). Whole K=96 in one shot.
// A-frag: lane reads h[m0+(lane&15)][quad*8 + s*32 .. +7] -> 16B contiguous global,
//   each node row read exactly once, wave footprint = 16 consecutive rows (3 KB).
// B-frag: W2 = [Wl;Wr] ([OT][96] B^T-form) staged fp32->bf16 into LDS in FRAG ORDER:
//   chunk ci = tile*3+step is 64 lanes x 16B contiguous -> ds_read_b128 at lane*16,
//   sequential = the 8-dword/bank minimum, zero conflicts.
// D layout (m89-verified): row(node) = quad*4+reg, col(out) = lane&15.
template <int DOUT, int NT>   // OT = 2*DOUT = NT*16, DIN = 96
__launch_bounds__(256, 4) static __global__
void transform_kernel(const ushort_t* __restrict__ hb, const float* __restrict__ Wl,
                      const float* __restrict__ bias, const float* __restrict__ Wr,
                      ushort_t* __restrict__ tlb, ushort_t* __restrict__ trb) {
    constexpr int DIN = 96;
    __shared__ short w_s[NT * 3 * 64 * 8];
    int tid = threadIdx.x;
    // stage weights (fp32 global -> bf16 LDS, frag-ordered)
    for (int idx = tid; idx < NT * 3 * 64; idx += 256) {
        int ci = idx >> 6, ln = idx & 63;
        int t = ci / 3, s = ci - 3 * t;
        int o = t * 16 + (ln & 15);
        int c0 = s * 32 + (ln >> 4) * 8;
        const float* wrow = (o < DOUT) ? (Wl + (size_t)o * DIN)
                                       : (Wr + (size_t)(o - DOUT) * DIN);
        float4 v0 = *(const float4*)(wrow + c0);
        float4 v1 = *(const float4*)(wrow + c0 + 4);
        bf16x8 pk;
        pk[0] = (short)f2b(v0.x); pk[1] = (short)f2b(v0.y);
        pk[2] = (short)f2b(v0.z); pk[3] = (short)f2b(v0.w);
        pk[4] = (short)f2b(v1.x); pk[5] = (short)f2b(v1.y);
        pk[6] = (short)f2b(v1.z); pk[7] = (short)f2b(v1.w);
        *(bf16x8*)&w_s[idx * 8] = pk;
    }
    int lane = tid & 63;
    int m0 = blockIdx.x * 64 + (tid >> 6) * 16;
    int row = m0 + (lane & 15);
    const bf16x8* arow = (const bf16x8*)(hb + (size_t)row * DIN) + (lane >> 4);
    bf16x8 a0 = arow[0];
    bf16x8 a1 = arow[4];
    bf16x8 a2 = arow[8];
    __syncthreads();
    const bf16x8* wp = (const bf16x8*)w_s + lane;
    f32x4 acc[NT];
#pragma unroll
    for (int t = 0; t < NT; t++) {
        acc[t] = (f32x4){0.f, 0.f, 0.f, 0.f};
        acc[t] = __builtin_amdgcn_mfma_f32_16x16x32_bf16(a0, wp[(t * 3 + 0) * 64], acc[t], 0, 0, 0);
        acc[t] = __builtin_amdgcn_mfma_f32_16x16x32_bf16(a1, wp[(t * 3 + 1) * 64], acc[t], 0, 0, 0);
        acc[t] = __builtin_amdgcn_mfma_f32_16x16x32_bf16(a2, wp[(t * 3 + 2) * 64], acc[t], 0, 0, 0);
    }
    int quad = lane >> 4, col = lane & 15;
#pragma unroll
    for (int t = 0; t < NT; t++) {
        int o = t * 16 + col;
        bool is_r = (o >= DOUT);                 // uniform per t
        float bv = is_r ? bias[o - DOUT] : 0.f;
        ushort_t* outp = is_r ? trb : tlb;
        int oo = is_r ? (o - DOUT) : o;
#pragma unroll
        for (int r = 0; r < 4; r++) {
            int node = m0 + quad * 4 + r;
            if (node < NN) outp[(size_t)node * DOUT + oo] = f2b(acc[t][r] + bv);
        }
    }
}

// ---------------- aggregation: out = relu?( mean_{j in N(i)} tl[j] + tr[i] ) ----------------
// bf16 rows; 16 lanes/node, lane owns dwords (lane + 16q) of the RD=D/2-dword row.
// fp32 accumulation; 4x unrolled gather (12 dword loads in flight per lane).
template <int D, bool RELU, bool OUT_BF16>
static __global__ void agg2_kernel(const ushort_t* __restrict__ tlb, const ushort_t* __restrict__ trb,
                                   const int* __restrict__ offs, const int* __restrict__ deg,
                                   const int* __restrict__ csr, void* __restrict__ outv) {
    constexpr int RD = D / 2;   // dwords per row
    constexpr int Q = D / 32;   // dwords per lane
    int gtid = blockIdx.x * 256 + threadIdx.x;
    int node = gtid >> 4;
    int lane = threadIdx.x & 15;
    if (node >= NN) return;
    int off = offs[node], dg = deg[node];
    const uint_t* tl32 = (const uint_t*)tlb;
    float acc[2 * Q];
#pragma unroll
    for (int q = 0; q < 2 * Q; q++) acc[q] = 0.f;
    int k = 0;
    for (; k + 4 <= dg; k += 4) {
        const uint_t* r0 = tl32 + (size_t)csr[off + k + 0] * RD;
        const uint_t* r1 = tl32 + (size_t)csr[off + k + 1] * RD;
        const uint_t* r2 = tl32 + (size_t)csr[off + k + 2] * RD;
        const uint_t* r3 = tl32 + (size_t)csr[off + k + 3] * RD;
#pragma unroll
        for (int q = 0; q < Q; q++) {
            uint_t u0 = r0[lane + 16 * q], u1 = r1[lane + 16 * q];
            uint_t u2 = r2[lane + 16 * q], u3 = r3[lane + 16 * q];
            acc[2 * q + 0] += (blo(u0) + blo(u1)) + (blo(u2) + blo(u3));
            acc[2 * q + 1] += (bhi(u0) + bhi(u1)) + (bhi(u2) + bhi(u3));
        }
    }
    for (; k < dg; k++) {
        const uint_t* r0 = tl32 + (size_t)csr[off + k] * RD;
#pragma unroll
        for (int q = 0; q < Q; q++) {
            uint_t u0 = r0[lane + 16 * q];
            acc[2 * q + 0] += blo(u0);
            acc[2 * q + 1] += bhi(u0);
        }
    }
    float s = 1.f / (float)max(dg, 1);
    const uint_t* trr = (const uint_t*)trb + (size_t)node * RD;
#pragma unroll
    for (int q = 0; q < Q; q++) {
        uint_t ut = trr[lane + 16 * q];
        float v0 = fmaf(acc[2 * q + 0], s, blo(ut));
        float v1 = fmaf(acc[2 * q + 1], s, bhi(ut));
        if (RELU) { v0 = fmaxf(v0, 0.f); v1 = fmaxf(v1, 0.f); }
        if (OUT_BF16) {
            ((uint_t*)outv)[(size_t)node * RD + lane + 16 * q] =
                (uint_t)f2b(v0) | ((uint_t)f2b(v1) << 16);
        } else {
            ((float2*)outv)[(size_t)node * RD + lane + 16 * q] = make_float2(v0, v1);
        }
    }
}

// ---------------- pooling over sorted batch ids (fp32 H) ----------------
static __global__ void pool_kernel(const float* __restrict__ h, const int* __restrict__ batch,
                                   float* __restrict__ accum, int* __restrict__ cnt) {
    int per = (NN + gridDim.x - 1) / gridDim.x;
    int start = blockIdx.x * per;
    int end = min(start + per, NN);
    if (start >= end) return;
    int c = threadIdx.x;                         // 64 features
    int gcur = batch[start];
    float acc = 0.f;
    int count = 0;
    for (int i = start; i < end; i++) {
        int g = batch[i];
        if (g != gcur) {
            atomicAdd(&accum[gcur * 64 + c], acc);
            if (c == 0) atomicAdd(&cnt[gcur], count);
            acc = 0.f; count = 0; gcur = g;
        }
        acc += h[(size_t)i * 64 + c];
        count++;
    }
    atomicAdd(&accum[gcur * 64 + c], acc);
    if (c == 0) atomicAdd(&cnt[gcur], count);
}

static __global__ void finalize_kernel(const float* __restrict__ accum, const int* __restrict__ cnt,
                                       float* __restrict__ out) {
    int i = blockIdx.x * 256 + threadIdx.x;
    if (i < NG * 64) {
        int g = i >> 6;
        out[i] = accum[i] / (float)max(cnt[g], 1);
    }
}

// ---------------- launch ----------------
extern "C" void kernel_launch(void* const* d_in, const int* in_sizes, int n_in,
                              void* d_out, int out_size, void* d_ws, size_t ws_size,
                              hipStream_t stream) {
    (void)in_sizes; (void)n_in; (void)out_size; (void)ws_size;
    const float* x   = (const float*)d_in[0];
    const int*   ei  = (const int*)d_in[1];
    const int*   bat = (const int*)d_in[2];
    const float* Wl0 = (const float*)d_in[3];
    const float* b0  = (const float*)d_in[4];
    const float* Wr0 = (const float*)d_in[5];
    const float* Wl1 = (const float*)d_in[6];
    const float* b1  = (const float*)d_in[7];
    const float* Wr1 = (const float*)d_in[8];
    const float* Wl2 = (const float*)d_in[9];
    const float* b2  = (const float*)d_in[10];
    const float* Wr2 = (const float*)d_in[11];
    float* out = (float*)d_out;
    const int* src = ei;
    const int* dst = ei + NE;

    char* p = (char*)d_ws;
    auto carve = [&](size_t bytes) -> char* {
        char* r = p;
        p += (bytes + 255) & ~(size_t)255;
        return r;
    };
    int*      deg    = (int*)carve((size_t)NN * 4);
    int*      offs   = (int*)carve((size_t)NN * 4);
    int*      cursor = (int*)carve((size_t)NN * 4);
    int*      bsums  = (int*)carve(128 * 4);
    int*      csr    = (int*)carve((size_t)NE * 4);
    int*      cnt    = (int*)carve(NG * 4);
    float*    accum  = (float*)carve((size_t)NG * 64 * 4);
    ushort_t* xb     = (ushort_t*)carve((size_t)NP * 96 * 2);   // layer-0 input; reused as h2b
    ushort_t* h1b    = (ushort_t*)carve((size_t)NP * 96 * 2);
    ushort_t* tlb    = (ushort_t*)carve((size_t)NP * 96 * 2);
    ushort_t* trb    = (ushort_t*)carve((size_t)NP * 96 * 2);
    float*    Hf     = (float*)carve((size_t)NN * 64 * 4);

    dim3 b256(256);
    zero_all_kernel<<<dim3((NN + 255) / 256), b256, 0, stream>>>(deg, cnt, accum);
    cvt_bf16_kernel<<<dim3((NN * 96 / 4 + 255) / 256), b256, 0, stream>>>(x, xb);

    hist_kernel<<<dim3((NE + 255) / 256), b256, 0, stream>>>(dst, deg);
    scan_block_kernel<<<dim3(NB_SCAN), dim3(SCAN_B), 0, stream>>>(deg, offs, bsums);
    scan_sums_kernel<<<dim3(1), dim3(128), 0, stream>>>(bsums);
    add_base_kernel<<<dim3(NB_SCAN), dim3(SCAN_B), 0, stream>>>(offs, bsums, cursor);
    fill_csr_kernel<<<dim3((NE + 255) / 256), b256, 0, stream>>>(src, dst, offs, cursor, csr);

    dim3 tGrid(NP / 64);                       // 782
    dim3 aGrid(NN * 16 / 256);                 // 3125

    // layer 0: 96 -> 96, relu
    transform_kernel<96, 12><<<tGrid, b256, 0, stream>>>(xb, Wl0, b0, Wr0, tlb, trb);
    agg2_kernel<96, true, true><<<aGrid, b256, 0, stream>>>(tlb, trb, offs, deg, csr, h1b);
    // layer 1: 96 -> 96, relu  (h2b reuses xb)
    transform_kernel<96, 12><<<tGrid, b256, 0, stream>>>(h1b, Wl1, b1, Wr1, tlb, trb);
    agg2_kernel<96, true, true><<<aGrid, b256, 0, stream>>>(tlb, trb, offs, deg, csr, xb);
    // layer 2: 96 -> 64, no relu, fp32 out for pooling
    transform_kernel<64, 8><<<tGrid, b256, 0, stream>>>(xb, Wl2, b2, Wr2, tlb, trb);
    agg2_kernel<64, false, false><<<aGrid, b256, 0, stream>>>(tlb, trb, offs, deg, csr, Hf);

    pool_kernel<<<dim3(512), dim3(64), 0, stream>>>(Hf, bat, accum, cnt);
    finalize_kernel<<<dim3((NG * 64 + 255) / 256), b256, 0, stream>>>(accum, cnt, out);
}

// Round 5
// 266.502 us; speedup vs baseline: 2.5865x; 1.2400x over previous
//
#include <hip/hip_runtime.h>
#include <stdint.h>
#include <stddef.h>

#define NN 50000
#define NP 50048            // padded rows (782 * 64) so MFMA A-frag OOB reads stay in-buffer
#define NE 800000
#define NG 128

#define NBKT 256            // dst buckets
#define NPB 196             // nodes per bucket (196*256 = 50176 >= NN)
#define BCAP 4096           // bucket capacity (mean 3136 + 17 sigma)
#define TILE_E 3200         // edges per partition workgroup (250 wgs)

typedef __attribute__((ext_vector_type(8))) short bf16x8;
typedef __attribute__((ext_vector_type(4))) float f32x4;
typedef unsigned short ushort_t;
typedef unsigned int uint_t;

// float -> bf16 (RNE) and bf16x2 unpack helpers
static __device__ inline ushort_t f2b(float f) {
    union { float f; uint_t u; } v; v.f = f;
    uint_t r = v.u + 0x7FFFu + ((v.u >> 16) & 1u);
    return (ushort_t)(r >> 16);
}
static __device__ inline float blo(uint_t u) {
    union { uint_t u; float f; } v; v.u = u << 16; return v.f;
}
static __device__ inline float bhi(uint_t u) {
    union { uint_t u; float f; } v; v.u = u & 0xFFFF0000u; return v.f;
}

// ---------------- utility ----------------
static __global__ void zero_all_kernel(int* __restrict__ bucket_cnt, int* __restrict__ cnt,
                                       float* __restrict__ accum) {
    int i = blockIdx.x * 256 + threadIdx.x;
    if (i < NBKT) bucket_cnt[i] = 0;
    if (i < NG) cnt[i] = 0;
    if (i < NG * 64) accum[i] = 0.f;
}

// x fp32 -> bf16 (4 elems/thread)
static __global__ void cvt_bf16_kernel(const float* __restrict__ x, ushort_t* __restrict__ xb) {
    int i = (blockIdx.x * 256 + threadIdx.x) * 4;
    if (i + 3 < NN * 96) {
        float4 v = *(const float4*)(x + i);
        ushort_t o0 = f2b(v.x), o1 = f2b(v.y), o2 = f2b(v.z), o3 = f2b(v.w);
        uint_t lo = (uint_t)o0 | ((uint_t)o1 << 16);
        uint_t hi = (uint_t)o2 | ((uint_t)o3 << 16);
        *(uint2*)(xb + i) = make_uint2(lo, hi);
    }
}

// ---------------- bucketed CSR build ----------------
// Phase 1: partition edges into 256 dst-buckets. LDS histogram + one global
// atomic per (wg, bucket) reservation; scatter writes land in per-wg contiguous
// runs (~12 edges = 48B) inside each bucket region -> write amplification ~1.3x
// instead of the 17x of a full-random 4B scatter (R4: WRITE_SIZE 55MB for 3.2MB).
__launch_bounds__(256) static __global__
void partition_kernel(const int* __restrict__ src, const int* __restrict__ dst,
                      int* __restrict__ bucket_cnt, uint_t* __restrict__ part) {
    __shared__ int hist[NBKT];
    int tid = threadIdx.x;
    hist[tid] = 0;
    __syncthreads();
    int base = blockIdx.x * TILE_E;
    uint_t pk[TILE_E / 256 + 1];
    int bk[TILE_E / 256 + 1];
    int cnt = 0;
    for (int i = base + tid; i < base + TILE_E; i += 256) {
        int s = src[i], d = dst[i];
        int b = d / NPB;
        int dl = d - b * NPB;
        pk[cnt] = ((uint_t)dl << 16) | (uint_t)s;
        bk[cnt] = b;
        cnt++;
        atomicAdd(&hist[b], 1);
    }
    __syncthreads();
    int r = atomicAdd(&bucket_cnt[tid], hist[tid]);   // reserve
    __syncthreads();
    hist[tid] = r;                                    // reuse as cursor
    __syncthreads();
    for (int j = 0; j < cnt; j++) {
        int p = atomicAdd(&hist[bk[j]], 1);
        part[bk[j] * BCAP + p] = pk[j];
    }
}

// Phase 2: scan bucket counts (1 wg)
static __global__ void bscan_kernel(const int* __restrict__ bucket_cnt, int* __restrict__ bbase) {
    __shared__ int s[NBKT];
    int tid = threadIdx.x;
    int v = bucket_cnt[tid];
    s[tid] = v;
    __syncthreads();
    for (int off = 1; off < NBKT; off <<= 1) {
        int t = (tid >= off) ? s[tid - off] : 0;
        __syncthreads();
        s[tid] += t;
        __syncthreads();
    }
    bbase[tid] = s[tid] - v;                          // exclusive
}

// Phase 3: per-bucket CSR + deg + offs, all global writes coalesced.
__launch_bounds__(256) static __global__
void csr_build_kernel(const uint_t* __restrict__ part, const int* __restrict__ bucket_cnt,
                      const int* __restrict__ bbase, int* __restrict__ deg,
                      int* __restrict__ offs, int* __restrict__ csr) {
    __shared__ uint_t stage[BCAP];
    __shared__ ushort_t cstage[BCAP];
    __shared__ int deg_l[NBKT];
    __shared__ int scan_l[NBKT];
    __shared__ int cur_l[NBKT];
    int b = blockIdx.x, tid = threadIdx.x;
    int n = bucket_cnt[b], base = bbase[b];
    deg_l[tid] = 0;
    __syncthreads();
    for (int i = tid; i < n; i += 256) {
        uint_t e = part[(size_t)b * BCAP + i];
        stage[i] = e;
        atomicAdd(&deg_l[e >> 16], 1);
    }
    __syncthreads();
    int v = deg_l[tid];
    scan_l[tid] = v;
    __syncthreads();
    for (int off = 1; off < NBKT; off <<= 1) {
        int t = (tid >= off) ? scan_l[tid - off] : 0;
        __syncthreads();
        scan_l[tid] += t;
        __syncthreads();
    }
    int ex = scan_l[tid] - v;                         // exclusive local offset
    scan_l[tid] = ex;
    cur_l[tid] = 0;
    __syncthreads();
    int g = b * NPB + tid;
    if (tid < NPB && g < NN) { deg[g] = v; offs[g] = base + ex; }
    for (int i = tid; i < n; i += 256) {
        uint_t e = stage[i];
        int dl = e >> 16;
        int p = atomicAdd(&cur_l[dl], 1);
        cstage[scan_l[dl] + p] = (ushort_t)(e & 0xFFFFu);
    }
    __syncthreads();
    for (int i = tid; i < n; i += 256) csr[base + i] = (int)cstage[i];
}

// ---------------- MFMA transform: tl = h@Wl.T ; tr = h@Wr.T + b (bf16 in/out, fp32 acc) ----
template <int DOUT, int NT>   // OT = 2*DOUT = NT*16, DIN = 96
__launch_bounds__(256, 4) static __global__
void transform_kernel(const ushort_t* __restrict__ hb, const float* __restrict__ Wl,
                      const float* __restrict__ bias, const float* __restrict__ Wr,
                      ushort_t* __restrict__ tlb, ushort_t* __restrict__ trb) {
    constexpr int DIN = 96;
    __shared__ short w_s[NT * 3 * 64 * 8];
    int tid = threadIdx.x;
    for (int idx = tid; idx < NT * 3 * 64; idx += 256) {
        int ci = idx >> 6, ln = idx & 63;
        int t = ci / 3, s = ci - 3 * t;
        int o = t * 16 + (ln & 15);
        int c0 = s * 32 + (ln >> 4) * 8;
        const float* wrow = (o < DOUT) ? (Wl + (size_t)o * DIN)
                                       : (Wr + (size_t)(o - DOUT) * DIN);
        float4 v0 = *(const float4*)(wrow + c0);
        float4 v1 = *(const float4*)(wrow + c0 + 4);
        bf16x8 pk;
        pk[0] = (short)f2b(v0.x); pk[1] = (short)f2b(v0.y);
        pk[2] = (short)f2b(v0.z); pk[3] = (short)f2b(v0.w);
        pk[4] = (short)f2b(v1.x); pk[5] = (short)f2b(v1.y);
        pk[6] = (short)f2b(v1.z); pk[7] = (short)f2b(v1.w);
        *(bf16x8*)&w_s[idx * 8] = pk;
    }
    int lane = tid & 63;
    int m0 = blockIdx.x * 64 + (tid >> 6) * 16;
    int row = m0 + (lane & 15);
    const bf16x8* arow = (const bf16x8*)(hb + (size_t)row * DIN) + (lane >> 4);
    bf16x8 a0 = arow[0];
    bf16x8 a1 = arow[4];
    bf16x8 a2 = arow[8];
    __syncthreads();
    const bf16x8* wp = (const bf16x8*)w_s + lane;
    f32x4 acc[NT];
#pragma unroll
    for (int t = 0; t < NT; t++) {
        acc[t] = (f32x4){0.f, 0.f, 0.f, 0.f};
        acc[t] = __builtin_amdgcn_mfma_f32_16x16x32_bf16(a0, wp[(t * 3 + 0) * 64], acc[t], 0, 0, 0);
        acc[t] = __builtin_amdgcn_mfma_f32_16x16x32_bf16(a1, wp[(t * 3 + 1) * 64], acc[t], 0, 0, 0);
        acc[t] = __builtin_amdgcn_mfma_f32_16x16x32_bf16(a2, wp[(t * 3 + 2) * 64], acc[t], 0, 0, 0);
    }
    int quad = lane >> 4, col = lane & 15;
#pragma unroll
    for (int t = 0; t < NT; t++) {
        int o = t * 16 + col;
        bool is_r = (o >= DOUT);
        float bv = is_r ? bias[o - DOUT] : 0.f;
        ushort_t* outp = is_r ? trb : tlb;
        int oo = is_r ? (o - DOUT) : o;
#pragma unroll
        for (int r = 0; r < 4; r++) {
            int node = m0 + quad * 4 + r;
            if (node < NN) outp[(size_t)node * DOUT + oo] = f2b(acc[t][r] + bv);
        }
    }
}

// ---------------- aggregation: out = relu?( mean_{j in N(i)} tl[j] + tr[i] ) ----------------
template <int D, bool RELU, bool OUT_BF16>
static __global__ void agg2_kernel(const ushort_t* __restrict__ tlb, const ushort_t* __restrict__ trb,
                                   const int* __restrict__ offs, const int* __restrict__ deg,
                                   const int* __restrict__ csr, void* __restrict__ outv) {
    constexpr int RD = D / 2;   // dwords per row
    constexpr int Q = D / 32;   // dwords per lane
    int gtid = blockIdx.x * 256 + threadIdx.x;
    int node = gtid >> 4;
    int lane = threadIdx.x & 15;
    if (node >= NN) return;
    int off = offs[node], dg = deg[node];
    const uint_t* tl32 = (const uint_t*)tlb;
    float acc[2 * Q];
#pragma unroll
    for (int q = 0; q < 2 * Q; q++) acc[q] = 0.f;
    int k = 0;
    for (; k + 4 <= dg; k += 4) {
        const uint_t* r0 = tl32 + (size_t)csr[off + k + 0] * RD;
        const uint_t* r1 = tl32 + (size_t)csr[off + k + 1] * RD;
        const uint_t* r2 = tl32 + (size_t)csr[off + k + 2] * RD;
        const uint_t* r3 = tl32 + (size_t)csr[off + k + 3] * RD;
#pragma unroll
        for (int q = 0; q < Q; q++) {
            uint_t u0 = r0[lane + 16 * q], u1 = r1[lane + 16 * q];
            uint_t u2 = r2[lane + 16 * q], u3 = r3[lane + 16 * q];
            acc[2 * q + 0] += (blo(u0) + blo(u1)) + (blo(u2) + blo(u3));
            acc[2 * q + 1] += (bhi(u0) + bhi(u1)) + (bhi(u2) + bhi(u3));
        }
    }
    for (; k < dg; k++) {
        const uint_t* r0 = tl32 + (size_t)csr[off + k] * RD;
#pragma unroll
        for (int q = 0; q < Q; q++) {
            uint_t u0 = r0[lane + 16 * q];
            acc[2 * q + 0] += blo(u0);
            acc[2 * q + 1] += bhi(u0);
        }
    }
    float s = 1.f / (float)max(dg, 1);
    const uint_t* trr = (const uint_t*)trb + (size_t)node * RD;
#pragma unroll
    for (int q = 0; q < Q; q++) {
        uint_t ut = trr[lane + 16 * q];
        float v0 = fmaf(acc[2 * q + 0], s, blo(ut));
        float v1 = fmaf(acc[2 * q + 1], s, bhi(ut));
        if (RELU) { v0 = fmaxf(v0, 0.f); v1 = fmaxf(v1, 0.f); }
        if (OUT_BF16) {
            ((uint_t*)outv)[(size_t)node * RD + lane + 16 * q] =
                (uint_t)f2b(v0) | ((uint_t)f2b(v1) << 16);
        } else {
            ((float2*)outv)[(size_t)node * RD + lane + 16 * q] = make_float2(v0, v1);
        }
    }
}

// ---------------- pooling over sorted batch ids (fp32 H) ----------------
static __global__ void pool_kernel(const float* __restrict__ h, const int* __restrict__ batch,
                                   float* __restrict__ accum, int* __restrict__ cnt) {
    int per = (NN + gridDim.x - 1) / gridDim.x;
    int start = blockIdx.x * per;
    int end = min(start + per, NN);
    if (start >= end) return;
    int c = threadIdx.x;                         // 64 features
    int gcur = batch[start];
    float acc = 0.f;
    int count = 0;
    for (int i = start; i < end; i++) {
        int g = batch[i];
        if (g != gcur) {
            atomicAdd(&accum[gcur * 64 + c], acc);
            if (c == 0) atomicAdd(&cnt[gcur], count);
            acc = 0.f; count = 0; gcur = g;
        }
        acc += h[(size_t)i * 64 + c];
        count++;
    }
    atomicAdd(&accum[gcur * 64 + c], acc);
    if (c == 0) atomicAdd(&cnt[gcur], count);
}

static __global__ void finalize_kernel(const float* __restrict__ accum, const int* __restrict__ cnt,
                                       float* __restrict__ out) {
    int i = blockIdx.x * 256 + threadIdx.x;
    if (i < NG * 64) {
        int g = i >> 6;
        out[i] = accum[i] / (float)max(cnt[g], 1);
    }
}

// ---------------- launch ----------------
extern "C" void kernel_launch(void* const* d_in, const int* in_sizes, int n_in,
                              void* d_out, int out_size, void* d_ws, size_t ws_size,
                              hipStream_t stream) {
    (void)in_sizes; (void)n_in; (void)out_size; (void)ws_size;
    const float* x   = (const float*)d_in[0];
    const int*   ei  = (const int*)d_in[1];
    const int*   bat = (const int*)d_in[2];
    const float* Wl0 = (const float*)d_in[3];
    const float* b0  = (const float*)d_in[4];
    const float* Wr0 = (const float*)d_in[5];
    const float* Wl1 = (const float*)d_in[6];
    const float* b1  = (const float*)d_in[7];
    const float* Wr1 = (const float*)d_in[8];
    const float* Wl2 = (const float*)d_in[9];
    const float* b2  = (const float*)d_in[10];
    const float* Wr2 = (const float*)d_in[11];
    float* out = (float*)d_out;
    const int* src = ei;
    const int* dst = ei + NE;

    char* p = (char*)d_ws;
    auto carve = [&](size_t bytes) -> char* {
        char* r = p;
        p += (bytes + 255) & ~(size_t)255;
        return r;
    };
    int*      deg    = (int*)carve((size_t)NN * 4);
    int*      offs   = (int*)carve((size_t)NN * 4);
    int*      bucket_cnt = (int*)carve(NBKT * 4);
    int*      bbase  = (int*)carve(NBKT * 4);
    uint_t*   part   = (uint_t*)carve((size_t)NBKT * BCAP * 4);
    int*      csr    = (int*)carve((size_t)NE * 4);
    int*      cnt    = (int*)carve(NG * 4);
    float*    accum  = (float*)carve((size_t)NG * 64 * 4);
    ushort_t* xb     = (ushort_t*)carve((size_t)NP * 96 * 2);   // layer-0 input; reused as h2b
    ushort_t* h1b    = (ushort_t*)carve((size_t)NP * 96 * 2);
    ushort_t* tlb    = (ushort_t*)carve((size_t)NP * 96 * 2);
    ushort_t* trb    = (ushort_t*)carve((size_t)NP * 96 * 2);
    float*    Hf     = (float*)carve((size_t)NN * 64 * 4);

    dim3 b256(256);
    zero_all_kernel<<<dim3((NG * 64 + 255) / 256), b256, 0, stream>>>(bucket_cnt, cnt, accum);
    cvt_bf16_kernel<<<dim3((NN * 96 / 4 + 255) / 256), b256, 0, stream>>>(x, xb);

    partition_kernel<<<dim3(NE / TILE_E), b256, 0, stream>>>(src, dst, bucket_cnt, part);
    bscan_kernel<<<dim3(1), b256, 0, stream>>>(bucket_cnt, bbase);
    csr_build_kernel<<<dim3(NBKT), b256, 0, stream>>>(part, bucket_cnt, bbase, deg, offs, csr);

    dim3 tGrid(NP / 64);                       // 782
    dim3 aGrid(NN * 16 / 256);                 // 3125

    // layer 0: 96 -> 96, relu
    transform_kernel<96, 12><<<tGrid, b256, 0, stream>>>(xb, Wl0, b0, Wr0, tlb, trb);
    agg2_kernel<96, true, true><<<aGrid, b256, 0, stream>>>(tlb, trb, offs, deg, csr, h1b);
    // layer 1: 96 -> 96, relu  (h2b reuses xb)
    transform_kernel<96, 12><<<tGrid, b256, 0, stream>>>(h1b, Wl1, b1, Wr1, tlb, trb);
    agg2_kernel<96, true, true><<<aGrid, b256, 0, stream>>>(tlb, trb, offs, deg, csr, xb);
    // layer 2: 96 -> 64, no relu, fp32 out for pooling
    transform_kernel<64, 8><<<tGrid, b256, 0, stream>>>(xb, Wl2, b2, Wr2, tlb, trb);
    agg2_kernel<64, false, false><<<aGrid, b256, 0, stream>>>(tlb, trb, offs, deg, csr, Hf);

    pool_kernel<<<dim3(512), dim3(64), 0, stream>>>(Hf, bat, accum, cnt);
    finalize_kernel<<<dim3((NG * 64 + 255) / 256), b256, 0, stream>>>(accum, cnt, out);
}